// Round 8
// baseline (591.217 us; speedup 1.0000x reference)
//
#include <hip/hip_runtime.h>
#include <hip/hip_bf16.h>
#include <cstdint>
#include <math.h>

// SEDformer block: BN-folded bf16 MFMA GEMMs + in-place chunked EMA scan + RFF linear attention.
// L=2048 BS=16 D=512 H=8 DH=64 R=48 HID=2048; rows NR = L*BS = 32768.
// R8: persistent multi-tile GEMM (T row-consecutive tiles per block, continuous k-loop,
// epilogue overlapped with next tile's staging); coalesced LDS-transpose weight folds.

typedef float  f32x4 __attribute__((ext_vector_type(4)));
typedef short  s16x8 __attribute__((ext_vector_type(8)));
typedef unsigned short u16x4 __attribute__((ext_vector_type(4)));

#define DEV static __device__ __forceinline__

constexpr int NR = 32768;          // L*BS

DEV float us2f(unsigned short u) {
  union { unsigned int i; float f; } z; z.i = ((unsigned int)u) << 16; return z.f;
}
DEV unsigned short f2bits(float f) {          // RNE f32 -> bf16 bits
  unsigned int u = __builtin_bit_cast(unsigned int, f);
  unsigned int r = u + 0x7fffu + ((u >> 16) & 1u);
  return (unsigned short)(r >> 16);
}

DEV void gload_lds16(const void* g, void* l) {
  __builtin_amdgcn_global_load_lds((__attribute__((address_space(1))) void*)g,
                                   (__attribute__((address_space(3))) void*)l, 16, 0, 0);
}

// ---------------- param prep: BN scale/shift + membrane betas + dot-acc zeroing ----------------
struct PrepArgs {
  const float *g[7], *b[7], *m[7], *v[7];   // bn1,bnq,bnk,bnv,bn2,bnf1,bnf2
  const float *wtq, *wtk;
  float *s[7], *t[7];
  float *betaq, *betak;
  float *dotqkv, *dot1;                     // 1536 / 2048, zeroed here
};

__global__ void prep_vectors(PrepArgs a) {
  int i = blockIdx.x * 256 + threadIdx.x;   // 0..2047
  const int dims[7] = {512, 512, 512, 512, 512, 2048, 512};
  #pragma unroll
  for (int k = 0; k < 7; ++k) {
    if (i < dims[k]) {
      float sc = a.g[k][i] * rsqrtf(a.v[k][i] + 1e-5f);
      a.s[k][i] = sc;
      a.t[k][i] = a.b[k][i] - a.m[k][i] * sc;
    }
  }
  if (i < 1536) a.dotqkv[i] = 0.f;
  if (i < 2048) a.dot1[i] = 0.f;
  if (i < 512) {
    float w = a.wtq[i];
    float sp = (w > 20.f) ? w : log1pf(expf(w));
    float be = 1.f - 1.f / (sp + 1.f);
    a.betaq[i] = fminf(fmaxf(be, 0.f), 0.9999f);
    w = a.wtk[i];
    sp = (w > 20.f) ? w : log1pf(expf(w));
    be = 1.f - 1.f / (sp + 1.f);
    a.betak[i] = fminf(fmaxf(be, 0.f), 0.9999f);
  }
}

// -------- coalesced fold: 64x64 LDS-transpose tile; W[K][Nn] -> WT bf16 [Nn][K] --------
// dot partials (tin . W) accumulated atomically into dotacc[j] for bias finalize.
__global__ void fold_wT2(const float* __restrict__ W, int K, int Nn,
                         const float* scin, const float* scout,
                         const float* tin, float* dotacc,
                         unsigned short* __restrict__ WT) {
  __shared__ float tile[64][65];
  __shared__ float dsum[4][64];
  const int j0 = blockIdx.x * 64, d0 = blockIdx.y * 64;
  const int tid = threadIdx.x;
  const int j = tid & 63, r = tid >> 6;
  float dpart = 0.f;
  #pragma unroll
  for (int i = 0; i < 16; ++i) {
    int dd = i * 4 + r;
    float w = W[(size_t)(d0 + dd) * Nn + j0 + j];
    tile[dd][j] = w;
    if (tin) dpart += tin[d0 + dd] * w;
  }
  if (tin) dsum[r][j] = dpart;
  __syncthreads();
  if (tin && r == 0)
    atomicAdd(&dotacc[j0 + j], dsum[0][j] + dsum[1][j] + dsum[2][j] + dsum[3][j]);
  const int d = j;
  const float si = scin ? scin[d0 + d] : 1.f;
  #pragma unroll
  for (int i = 0; i < 16; ++i) {
    int jj = i * 4 + r;
    float so = scout ? scout[j0 + jj] : 1.f;
    WT[(size_t)(j0 + jj) * K + d0 + d] = f2bits(tile[d][jj] * si * so);
  }
}

// -------- legacy per-column fold (kept for tiny rffW: K=64, N=48) --------
__global__ void fold_wT(const float* __restrict__ W, int K, int Nn,
                        unsigned short* __restrict__ WT) {
  int j = blockIdx.x;
  int lane = threadIdx.x;   // 64
  for (int dd = lane; dd < K; dd += 64)
    WT[(size_t)j * K + dd] = f2bits(W[(size_t)dd * Nn + j]);
}

// -------- bias finalize --------
struct BiasArgs {
  const float *dotqkv, *dot1, *bv, *fc1b, *fc2b;
  const float *s1, *t1, *s2, *t2, *s3, *t3, *s5, *t5, *s6, *t6;
  float *c_qkv, *c1, *c2;
};
__global__ void bias_fin(BiasArgs a) {
  int i = blockIdx.x * 256 + threadIdx.x;   // 0..2047
  if (i < 512) {
    a.c_qkv[i]        = a.s1[i] * a.dotqkv[i]        + a.t1[i];
    a.c_qkv[512 + i]  = a.s2[i] * a.dotqkv[512 + i]  + a.t2[i];
    a.c_qkv[1024 + i] = a.s3[i] * (a.dotqkv[1024 + i] + a.bv[i]) + a.t3[i];
    a.c2[i]           = a.s6[i] * a.fc2b[i] + a.t6[i];
  }
  if (i < 2048) a.c1[i] = a.s5[i] * (a.dot1[i] + a.fc1b[i]) + a.t5[i];
}

// ---------------- cast x f32 -> bf16 ----------------
__global__ void cast_x(const float* __restrict__ x, unsigned short* __restrict__ xb, int n) {
  int i = (blockIdx.x * blockDim.x + threadIdx.x) * 4;
  if (i >= n) return;
  float4 v = *(const float4*)(x + i);
  u16x4 o = {f2bits(v.x), f2bits(v.y), f2bits(v.z), f2bits(v.w)};
  *(u16x4*)(xb + i) = o;
}

// ---------------- persistent GEMM: C[M,N] = A[M,K](bf16) * BT[N,K]^T + bias ----------------
// Each block processes T row-consecutive 128x128 tiles (same column) as ONE continuous
// double-buffered k-loop; epilogues fire at tile boundaries and overlap next tile's staging.
// Tile id gt: row-tile = gt & 255 (M=32768 fixed), col-tile = gt >> 8.
// MODE 0: outb = bf16(acc+bias)
// MODE 1: outb = bf16(us2f(xresb) + acc + bias)
// MODE 2: outb = bf16(gelu(acc+bias))   (sigmoid-form tanh gelu)
// MODE 3: outf = us2f(xresb) + acc + bias
template <int MODE>
__global__ __launch_bounds__(256, 2) void gemm_bf16(
    const unsigned short* __restrict__ A, const unsigned short* __restrict__ BT,
    int K, int lognt, int T, int Nn, const float* __restrict__ bias,
    const unsigned short* __restrict__ xresb,
    float* __restrict__ outf, unsigned short* __restrict__ outb) {
  __shared__ __align__(16) unsigned short Ab[2][128 * 32];
  __shared__ __align__(16) unsigned short Bb[2][128 * 32];
  const int tid = threadIdx.x, w = tid >> 6, lane = tid & 63;
  const int l15 = lane & 15, lg = lane >> 4;
  const int wr = w >> 1, wc = w & 1;
  const int blkT = blockIdx.x * T;

  auto stage = [&](int buf, int gt, int kt) {
    const unsigned short* Abase = A + (size_t)((gt & 255) << 7) * K;
    const unsigned short* Bbase = BT + (size_t)((gt >> 8) << 7) * K;
    #pragma unroll
    for (int s = 0; s < 2; ++s) {
      int c = s * 256 + w * 64 + lane;
      gload_lds16(Abase + (size_t)(c >> 2) * K + kt * 32 + (c & 3) * 8,
                  &Ab[buf][(s * 256 + w * 64) * 8]);
      gload_lds16(Bbase + (size_t)(c >> 2) * K + kt * 32 + (c & 3) * 8,
                  &Bb[buf][(s * 256 + w * 64) * 8]);
    }
  };

  const f32x4 fz = {0.f, 0.f, 0.f, 0.f};
  f32x4 acc[4][4];
  #pragma unroll
  for (int m = 0; m < 4; ++m)
    #pragma unroll
    for (int n = 0; n < 4; ++n) acc[m][n] = fz;

  const int nt = 1 << lognt;
  const int S = T << lognt;
  stage(0, blkT, 0);
  __syncthreads();
  int cur = 0;
  for (int s = 0; s < S; ++s) {
    if (s + 1 < S) {
      int ns = s + 1;
      stage(cur ^ 1, blkT + (ns >> lognt), ns & (nt - 1));
    }
    s16x8 af[4], bf[4];
    #pragma unroll
    for (int m = 0; m < 4; ++m)
      af[m] = *(const s16x8*)&Ab[cur][(wr * 64 + m * 16 + l15) * 32 + lg * 8];
    #pragma unroll
    for (int n = 0; n < 4; ++n)
      bf[n] = *(const s16x8*)&Bb[cur][(wc * 64 + n * 16 + l15) * 32 + lg * 8];
    #pragma unroll
    for (int m = 0; m < 4; ++m)
      #pragma unroll
      for (int n = 0; n < 4; ++n)
        acc[m][n] = __builtin_amdgcn_mfma_f32_16x16x32_bf16(af[m], bf[n], acc[m][n], 0, 0, 0);

    if ((s & (nt - 1)) == nt - 1) {
      // tile boundary: epilogue for tile gt (register-only + global stores; next tile's
      // first stage is already in flight)
      const int gt = blkT + (s >> lognt);
      const int row0 = (gt & 255) << 7, col0 = (gt >> 8) << 7;
      #pragma unroll
      for (int m = 0; m < 4; ++m) {
        #pragma unroll
        for (int q = 0; q < 4; ++q) {
          int row = row0 + wr * 64 + m * 16 + lg * 4 + q;
          #pragma unroll
          for (int n = 0; n < 4; ++n) {
            int col = col0 + wc * 64 + n * 16 + l15;
            float v = acc[m][n][q] + bias[col];
            size_t idx = (size_t)row * Nn + col;
            if constexpr (MODE == 0) {
              outb[idx] = f2bits(v);
            } else if constexpr (MODE == 1) {
              outb[idx] = f2bits(us2f(xresb[idx]) + v);
            } else if constexpr (MODE == 2) {
              float u2 = v * 1.5957691216f * (1.f + 0.044715f * v * v);
              float gl = v / (1.f + __expf(-u2));
              outb[idx] = f2bits(gl);
            } else {
              outf[idx] = us2f(xresb[idx]) + v;
            }
          }
        }
      }
      #pragma unroll
      for (int m = 0; m < 4; ++m)
        #pragma unroll
        for (int n = 0; n < 4; ++n) acc[m][n] = fz;
    }
    __syncthreads();
    cur ^= 1;
  }
}

// ---------------- membrane EMA scan over L, IN-PLACE, coalesced, 8-wide batched ----------------
__global__ __launch_bounds__(1024) void mem_scan2(unsigned short* __restrict__ qkv,
                         const float* __restrict__ betaq, const float* __restrict__ betak) {
  __shared__ float carry[16][64];
  __shared__ float pre[16][64];
  int cg = blockIdx.x & 15, b = blockIdx.x >> 4;
  int w = threadIdx.x >> 6, lane = threadIdx.x & 63;
  int ch = cg * 64 + lane;
  const float beta = (ch < 512) ? betaq[ch] : betak[ch - 512];
  const float om = 1.f - beta;
  unsigned short* base = qkv + (size_t)b * 1536 + ch;
  const size_t rs = 16 * 1536;     // shorts per L-step
  const int l0 = w * 128;

  float m = 0.f;
  for (int i = 0; i < 128; i += 8) {
    float v[8];
    #pragma unroll
    for (int j = 0; j < 8; ++j) v[j] = us2f(base[(size_t)(l0 + i + j) * rs]);
    #pragma unroll
    for (int j = 0; j < 8; ++j) m = beta * m + om * v[j];
  }
  carry[w][lane] = m;
  __syncthreads();
  if (w == 0) {
    float pw = beta;
    #pragma unroll
    for (int t = 0; t < 7; ++t) pw *= pw;   // beta^128
    float run = 0.f;
    for (int cc = 0; cc < 16; ++cc) {
      pre[cc][lane] = run;
      run = carry[cc][lane] + pw * run;
    }
  }
  __syncthreads();
  m = pre[w][lane];
  for (int i = 0; i < 128; i += 8) {
    float v[8];
    #pragma unroll
    for (int j = 0; j < 8; ++j) v[j] = us2f(base[(size_t)(l0 + i + j) * rs]);
    #pragma unroll
    for (int j = 0; j < 8; ++j) {
      m = beta * m + om * v[j];
      base[(size_t)(l0 + i + j) * rs] = f2bits(m);
    }
  }
}

// ---------------- transpose v: qkv v-cols -> vT[b,h,dh][L] ----------------
__global__ void transpose_v(const unsigned short* __restrict__ qkv, unsigned short* __restrict__ vT) {
  __shared__ __align__(16) unsigned short tile[64][72];
  int bid = blockIdx.x;
  int lt = bid & 31, h = (bid >> 5) & 7, b = bid >> 8;
  int l0 = lt * 64;
  int tid = threadIdx.x;
  int r = tid >> 2, cg = (tid & 3) * 16;
  const unsigned short* src = qkv + (size_t)((l0 + r) * 16 + b) * 1536 + 1024 + h * 64 + cg;
  *(s16x8*)&tile[r][cg] = *(const s16x8*)(src);
  *(s16x8*)&tile[r][cg + 8] = *(const s16x8*)(src + 8);
  __syncthreads();
  int dh = tid >> 2, lgp = (tid & 3) * 16;
  s16x8 o0, o1;
  #pragma unroll
  for (int j = 0; j < 8; ++j) {
    o0[j] = (short)tile[lgp + j][dh];
    o1[j] = (short)tile[lgp + 8 + j][dh];
  }
  unsigned short* dstp = vT + (size_t)((b * 8 + h) * 64 + dh) * 2048 + l0 + lgp;
  *(s16x8*)dstp = o0;
  *(s16x8*)(dstp + 8) = o1;
}

// ---------------- RFF linear attention phase A: KV + Ksum partials (no global atomics) ----------
__global__ __launch_bounds__(512, 1) void attn_A(
    const unsigned short* __restrict__ qkv, const unsigned short* __restrict__ vT,
    const unsigned short* __restrict__ WrT, const float* __restrict__ rffb,
    float* __restrict__ KVg, float* __restrict__ Ksumg) {
  __shared__ float KV[48][64];
  __shared__ float Ksum[48];
  __shared__ __align__(16) unsigned short phiT[8][48][72];

  const int tid = threadIdx.x;
  const int w = tid >> 6, lane = tid & 63, l15 = lane & 15, lg = lane >> 4;
  const int bh = blockIdx.x, b = bh >> 3, h = bh & 7;
  const int half = blockIdx.y;
  const f32x4 fz = {0.f, 0.f, 0.f, 0.f};
  constexpr float ISR = 0.14433756729740643f;   // 1/sqrt(48)

  for (int i = tid; i < 48 * 64; i += 512) (&KV[0][0])[i] = 0.f;
  if (tid < 48) Ksum[tid] = 0.f;
  __syncthreads();

  s16x8 wf[3][2];
  float bias_n[3];
  #pragma unroll
  for (int n = 0; n < 3; ++n) {
    int r = n * 16 + l15;
    bias_n[n] = rffb[h * 48 + r];
    #pragma unroll
    for (int ks = 0; ks < 2; ++ks)
      wf[n][ks] = *(const s16x8*)(WrT + (size_t)(h * 48 + r) * 64 + ks * 32 + lg * 8);
  }

  f32x4 kv[3][4];
  #pragma unroll
  for (int mm = 0; mm < 3; ++mm)
    #pragma unroll
    for (int nn = 0; nn < 4; ++nn) kv[mm][nn] = fz;
  float ks_acc[3] = {0.f, 0.f, 0.f};
  const size_t vbase = (size_t)(b * 8 + h) * 64 * 2048;

  for (int c = half * 16 + w; c < half * 16 + 16; c += 8) {
    const int l0 = c * 64;
    s16x8 kf[4][2];
    #pragma unroll
    for (int m = 0; m < 4; ++m) {
      size_t ro = (size_t)((l0 + m * 16 + l15) * 16 + b) * 1536 + 512 + h * 64;
      #pragma unroll
      for (int ks = 0; ks < 2; ++ks)
        kf[m][ks] = *(const s16x8*)(qkv + ro + ks * 32 + lg * 8);
    }
    f32x4 p[4][3];
    #pragma unroll
    for (int m = 0; m < 4; ++m)
      #pragma unroll
      for (int n = 0; n < 3; ++n) {
        p[m][n] = fz + bias_n[n];
        #pragma unroll
        for (int ks = 0; ks < 2; ++ks)
          p[m][n] = __builtin_amdgcn_mfma_f32_16x16x32_bf16(kf[m][ks], wf[n][ks], p[m][n], 0, 0, 0);
      }
    #pragma unroll
    for (int m = 0; m < 4; ++m)
      #pragma unroll
      for (int n = 0; n < 3; ++n) {
        u16x4 pk;
        #pragma unroll
        for (int q = 0; q < 4; ++q) {
          float pv = p[m][n][q];
          float ph = (pv > 0.f ? pv + 1.000001f : __expf(pv) + 1e-6f) * ISR;
          ks_acc[n] += ph;
          pk[q] = f2bits(ph);
        }
        *(u16x4*)&phiT[w][n * 16 + l15][m * 16 + lg * 4] = pk;
      }
    s16x8 pf[3][2], vf[4][2];
    #pragma unroll
    for (int mm = 0; mm < 3; ++mm)
      #pragma unroll
      for (int ks = 0; ks < 2; ++ks)
        pf[mm][ks] = *(const s16x8*)&phiT[w][mm * 16 + l15][ks * 32 + lg * 8];
    #pragma unroll
    for (int nn = 0; nn < 4; ++nn)
      #pragma unroll
      for (int ks = 0; ks < 2; ++ks)
        vf[nn][ks] = *(const s16x8*)(vT + vbase + (size_t)(nn * 16 + l15) * 2048 + l0 + ks * 32 + lg * 8);
    #pragma unroll
    for (int mm = 0; mm < 3; ++mm)
      #pragma unroll
      for (int nn = 0; nn < 4; ++nn)
        #pragma unroll
        for (int ks = 0; ks < 2; ++ks)
          kv[mm][nn] = __builtin_amdgcn_mfma_f32_16x16x32_bf16(pf[mm][ks], vf[nn][ks], kv[mm][nn], 0, 0, 0);
  }
  #pragma unroll
  for (int n = 0; n < 3; ++n) {
    float t = ks_acc[n];
    t += __shfl_xor(t, 16);
    t += __shfl_xor(t, 32);
    if (lane < 16) atomicAdd(&Ksum[n * 16 + lane], t);
  }
  #pragma unroll
  for (int mm = 0; mm < 3; ++mm)
    #pragma unroll
    for (int nn = 0; nn < 4; ++nn)
      #pragma unroll
      for (int q = 0; q < 4; ++q)
        atomicAdd(&KV[mm * 16 + lg * 4 + q][nn * 16 + l15], kv[mm][nn][q]);
  __syncthreads();

  float* dst = KVg + (size_t)(half * 128 + bh) * 3072;
  for (int i = tid; i < 48 * 64; i += 512) dst[i] = (&KV[0][0])[i];
  if (tid < 48) Ksumg[(half * 128 + bh) * 48 + tid] = Ksum[tid];
}

// ---------------- RFF linear attention phase B: phi_q, num/den, output ----------------
__global__ __launch_bounds__(512, 1) void attn_B(
    const unsigned short* __restrict__ qkv, const unsigned short* __restrict__ WrT,
    const float* __restrict__ rffb, const float* __restrict__ KVg,
    const float* __restrict__ Ksumg, unsigned short* __restrict__ attn) {
  __shared__ __align__(16) unsigned short KVT[80][72];
  __shared__ __align__(16) unsigned short phiQ[8][64][72];

  const int tid = threadIdx.x;
  const int w = tid >> 6, lane = tid & 63, l15 = lane & 15, lg = lane >> 4;
  const int bh = blockIdx.x, b = bh >> 3, h = bh & 7;
  const int half = blockIdx.y;
  const f32x4 fz = {0.f, 0.f, 0.f, 0.f};
  constexpr float ISR = 0.14433756729740643f;   // 1/sqrt(48)

  for (int i = tid; i < 8 * 64 * 72; i += 512) (&phiQ[0][0][0])[i] = 0;
  for (int i = tid; i < 80 * 72; i += 512) {
    int dhe = i / 72, rr = i - dhe * 72;
    float val = 0.f;
    if (rr < 48) {
      if (dhe < 64)
        val = KVg[(size_t)bh * 3072 + rr * 64 + dhe] + KVg[(size_t)(128 + bh) * 3072 + rr * 64 + dhe];
      else if (dhe == 64)
        val = fmaxf(Ksumg[bh * 48 + rr] + Ksumg[(128 + bh) * 48 + rr], 1e-6f);
    }
    (&KVT[0][0])[i] = f2bits(val);
  }
  __syncthreads();

  s16x8 wf[3][2];
  float bias_n[3];
  #pragma unroll
  for (int n = 0; n < 3; ++n) {
    int r = n * 16 + l15;
    bias_n[n] = rffb[h * 48 + r];
    #pragma unroll
    for (int ks = 0; ks < 2; ++ks)
      wf[n][ks] = *(const s16x8*)(WrT + (size_t)(h * 48 + r) * 64 + ks * 32 + lg * 8);
  }

  for (int c = half * 16 + w; c < half * 16 + 16; c += 8) {
    const int l0 = c * 64;
    s16x8 qf[4][2];
    #pragma unroll
    for (int m = 0; m < 4; ++m) {
      size_t ro = (size_t)((l0 + m * 16 + l15) * 16 + b) * 1536 + h * 64;
      #pragma unroll
      for (int ks = 0; ks < 2; ++ks)
        qf[m][ks] = *(const s16x8*)(qkv + ro + ks * 32 + lg * 8);
    }
    f32x4 p[4][3];
    #pragma unroll
    for (int m = 0; m < 4; ++m)
      #pragma unroll
      for (int n = 0; n < 3; ++n) {
        p[m][n] = fz + bias_n[n];
        #pragma unroll
        for (int ks = 0; ks < 2; ++ks)
          p[m][n] = __builtin_amdgcn_mfma_f32_16x16x32_bf16(qf[m][ks], wf[n][ks], p[m][n], 0, 0, 0);
      }
    #pragma unroll
    for (int m = 0; m < 4; ++m)
      #pragma unroll
      for (int n = 0; n < 3; ++n)
        #pragma unroll
        for (int q = 0; q < 4; ++q) {
          float pv = p[m][n][q];
          float ph = (pv > 0.f ? pv + 1.000001f : __expf(pv) + 1e-6f) * ISR;
          phiQ[w][m * 16 + lg * 4 + q][n * 16 + l15] = f2bits(ph);
        }
    s16x8 af[4][2], bv8[5][2];
    #pragma unroll
    for (int m = 0; m < 4; ++m)
      #pragma unroll
      for (int ks = 0; ks < 2; ++ks)
        af[m][ks] = *(const s16x8*)&phiQ[w][m * 16 + l15][ks * 32 + lg * 8];
    #pragma unroll
    for (int n5 = 0; n5 < 5; ++n5)
      #pragma unroll
      for (int ks = 0; ks < 2; ++ks)
        bv8[n5][ks] = *(const s16x8*)&KVT[n5 * 16 + l15][ks * 32 + lg * 8];
    f32x4 o[4][5];
    #pragma unroll
    for (int m = 0; m < 4; ++m)
      #pragma unroll
      for (int n5 = 0; n5 < 5; ++n5) {
        o[m][n5] = fz;
        #pragma unroll
        for (int ks = 0; ks < 2; ++ks)
          o[m][n5] = __builtin_amdgcn_mfma_f32_16x16x32_bf16(af[m][ks], bv8[n5][ks], o[m][n5], 0, 0, 0);
      }
    #pragma unroll
    for (int m = 0; m < 4; ++m)
      #pragma unroll
      for (int q = 0; q < 4; ++q) {
        float den = __shfl(o[m][4][q], lane & 48);
        float inv = 1.f / (den + 1e-6f);
        int gl = l0 + m * 16 + lg * 4 + q;
        size_t ob = (size_t)(gl * 16 + b) * 512 + h * 64;
        #pragma unroll
        for (int n = 0; n < 4; ++n)
          attn[ob + n * 16 + l15] = f2bits(o[m][n][q] * inv);
      }
  }
}

// ---------------- host ----------------
extern "C" void kernel_launch(void* const* d_in, const int* in_sizes, int n_in,
                              void* d_out, int out_size, void* d_ws, size_t ws_size,
                              hipStream_t stream) {
  (void)in_sizes; (void)n_in; (void)out_size; (void)ws_size;
  const float* x = (const float*)d_in[0];
  const float* Wq = (const float*)d_in[29];
  const float* Wk = (const float*)d_in[30];
  const float* Wv = (const float*)d_in[31];
  const float* bv = (const float*)d_in[32];
  const float* Wo = (const float*)d_in[33];
  const float* bo = (const float*)d_in[34];
  const float* wtq = (const float*)d_in[35];
  const float* wtk = (const float*)d_in[36];
  const float* rffW = (const float*)d_in[37];
  const float* rffb = (const float*)d_in[38];
  const float* fc1W = (const float*)d_in[39];
  const float* fc1b = (const float*)d_in[40];
  const float* fc2W = (const float*)d_in[41];
  const float* fc2b = (const float*)d_in[42];

  char* cur = (char*)d_ws;
  auto alloc = [&](size_t bytes) -> char* {
    char* r = cur;
    cur += (bytes + 255) & ~(size_t)255;
    return r;
  };
  float* sv_[7];
  float* tv_[7];
  const int dims[7] = {512, 512, 512, 512, 512, 2048, 512};
  for (int k = 0; k < 7; ++k) {
    sv_[k] = (float*)alloc(dims[k] * 4);
    tv_[k] = (float*)alloc(dims[k] * 4);
  }
  float* betaq = (float*)alloc(512 * 4);
  float* betak = (float*)alloc(512 * 4);
  float* c_qkv = (float*)alloc(1536 * 4);
  float* c1 = (float*)alloc(2048 * 4);
  float* c2 = (float*)alloc(512 * 4);
  float* dotqkv = (float*)alloc(1536 * 4);
  float* dot1   = (float*)alloc(2048 * 4);
  float* KVg   = (float*)alloc((size_t)256 * 3072 * 4);   // [half*128+bh][3072]
  float* Ksumg = (float*)alloc((size_t)256 * 48 * 4);
  unsigned short* AqkvT = (unsigned short*)alloc((size_t)1536 * 512 * 2);
  unsigned short* WoT   = (unsigned short*)alloc((size_t)512 * 512 * 2);
  unsigned short* A1T   = (unsigned short*)alloc((size_t)2048 * 512 * 2);
  unsigned short* A2T   = (unsigned short*)alloc((size_t)512 * 2048 * 2);
  unsigned short* WrT   = (unsigned short*)alloc((size_t)8 * 48 * 64 * 2);
  // big buffers (qkv and vT MUST be adjacent: g overlays both exactly)
  unsigned short* qkv   = (unsigned short*)alloc((size_t)NR * 1536 * 2);  // 96 MiB
  unsigned short* vT    = (unsigned short*)alloc((size_t)NR * 512 * 2);   // 32 MiB: vT then attn-out
  unsigned short* xb    = (unsigned short*)alloc((size_t)NR * 512 * 2);   // 32 MiB: bf16(x), lives to wo
  unsigned short* xrb   = (unsigned short*)alloc((size_t)NR * 512 * 2);   // 32 MiB
  unsigned short* attnO = vT;          // attn output reuses vT (dead after attn_A)
  unsigned short* g = qkv;             // fc1-out [NR][2048] bf16 = 128 MiB over qkv+vT (both dead)

  PrepArgs pa;
  for (int k = 0; k < 7; ++k) {
    pa.g[k] = (const float*)d_in[1 + k * 4 + 0];
    pa.b[k] = (const float*)d_in[1 + k * 4 + 1];
    pa.m[k] = (const float*)d_in[1 + k * 4 + 2];
    pa.v[k] = (const float*)d_in[1 + k * 4 + 3];
    pa.s[k] = sv_[k];
    pa.t[k] = tv_[k];
  }
  pa.wtq = wtq; pa.wtk = wtk; pa.betaq = betaq; pa.betak = betak;
  pa.dotqkv = dotqkv; pa.dot1 = dot1;

  prep_vectors<<<8, 256, 0, stream>>>(pa);
  // coalesced folds (64x64 tiles): grid (Nn/64, K/64)
  fold_wT2<<<dim3(8, 8), 256, 0, stream>>>(Wq, 512, 512, sv_[0], sv_[1], tv_[0], dotqkv, AqkvT);
  fold_wT2<<<dim3(8, 8), 256, 0, stream>>>(Wk, 512, 512, sv_[0], sv_[2], tv_[0], dotqkv + 512, AqkvT + 512 * 512);
  fold_wT2<<<dim3(8, 8), 256, 0, stream>>>(Wv, 512, 512, sv_[0], sv_[3], tv_[0], dotqkv + 1024, AqkvT + 1024 * 512);
  fold_wT2<<<dim3(8, 8), 256, 0, stream>>>(Wo, 512, 512, nullptr, nullptr, nullptr, nullptr, WoT);
  fold_wT2<<<dim3(32, 8), 256, 0, stream>>>(fc1W, 512, 2048, sv_[4], sv_[5], tv_[4], dot1, A1T);
  fold_wT2<<<dim3(8, 32), 256, 0, stream>>>(fc2W, 2048, 512, nullptr, sv_[6], nullptr, nullptr, A2T);
  for (int h = 0; h < 8; ++h)
    fold_wT<<<48, 64, 0, stream>>>(rffW + h * 64 * 48, 64, 48, WrT + h * 48 * 64);

  BiasArgs ba;
  ba.dotqkv = dotqkv; ba.dot1 = dot1; ba.bv = bv; ba.fc1b = fc1b; ba.fc2b = fc2b;
  ba.s1 = sv_[1]; ba.t1 = tv_[1]; ba.s2 = sv_[2]; ba.t2 = tv_[2]; ba.s3 = sv_[3]; ba.t3 = tv_[3];
  ba.s5 = sv_[5]; ba.t5 = tv_[5]; ba.s6 = sv_[6]; ba.t6 = tv_[6];
  ba.c_qkv = c_qkv; ba.c1 = c1; ba.c2 = c2;
  bias_fin<<<8, 256, 0, stream>>>(ba);

  cast_x<<<16384, 256, 0, stream>>>(x, xb, NR * 512);
  // persistent GEMMs: 512 blocks (2/CU); tiles per block T, row-consecutive (same column)
  gemm_bf16<0><<<512, 256, 0, stream>>>(xb, AqkvT, 512, 4, 6, 1536, c_qkv, nullptr, nullptr, qkv);
  mem_scan2<<<256, 1024, 0, stream>>>(qkv, betaq, betak);
  transpose_v<<<4096, 256, 0, stream>>>(qkv, vT);
  attn_A<<<dim3(128, 2), 512, 0, stream>>>(qkv, vT, WrT, rffb, KVg, Ksumg);
  attn_B<<<dim3(128, 2), 512, 0, stream>>>(qkv, WrT, rffb, KVg, Ksumg, attnO);
  gemm_bf16<1><<<512, 256, 0, stream>>>(attnO, WoT, 512, 4, 2, 512, bo, xb, nullptr, xrb);
  gemm_bf16<2><<<512, 256, 0, stream>>>(xrb, A1T, 512, 4, 8, 2048, c1, nullptr, nullptr, g);
  gemm_bf16<3><<<512, 256, 0, stream>>>(g, A2T, 2048, 6, 2, 512, c2, xrb, (float*)d_out, nullptr);
}

// Round 9
// 545.418 us; speedup vs baseline: 1.0840x; 1.0840x over previous
//
#include <hip/hip_runtime.h>
#include <hip/hip_bf16.h>
#include <cstdint>
#include <math.h>

// SEDformer block: BN-folded bf16 MFMA GEMMs + in-place chunked EMA scan + RFF linear attention.
// L=2048 BS=16 D=512 H=8 DH=64 R=48 HID=2048; rows NR = L*BS = 32768.
// R9: revert to per-tile 2D-grid GEMM (R6 structure, best measured); keep coalesced folds;
// launch_bounds(256,4) occupancy hint.

typedef float  f32x4 __attribute__((ext_vector_type(4)));
typedef short  s16x8 __attribute__((ext_vector_type(8)));
typedef unsigned short u16x4 __attribute__((ext_vector_type(4)));

#define DEV static __device__ __forceinline__

constexpr int NR = 32768;          // L*BS

DEV float us2f(unsigned short u) {
  union { unsigned int i; float f; } z; z.i = ((unsigned int)u) << 16; return z.f;
}
DEV unsigned short f2bits(float f) {          // RNE f32 -> bf16 bits
  unsigned int u = __builtin_bit_cast(unsigned int, f);
  unsigned int r = u + 0x7fffu + ((u >> 16) & 1u);
  return (unsigned short)(r >> 16);
}

DEV void gload_lds16(const void* g, void* l) {
  __builtin_amdgcn_global_load_lds((__attribute__((address_space(1))) void*)g,
                                   (__attribute__((address_space(3))) void*)l, 16, 0, 0);
}

// ---------------- param prep: BN scale/shift + membrane betas + dot-acc zeroing ----------------
struct PrepArgs {
  const float *g[7], *b[7], *m[7], *v[7];   // bn1,bnq,bnk,bnv,bn2,bnf1,bnf2
  const float *wtq, *wtk;
  float *s[7], *t[7];
  float *betaq, *betak;
  float *dotqkv, *dot1;                     // 1536 / 2048, zeroed here
};

__global__ void prep_vectors(PrepArgs a) {
  int i = blockIdx.x * 256 + threadIdx.x;   // 0..2047
  const int dims[7] = {512, 512, 512, 512, 512, 2048, 512};
  #pragma unroll
  for (int k = 0; k < 7; ++k) {
    if (i < dims[k]) {
      float sc = a.g[k][i] * rsqrtf(a.v[k][i] + 1e-5f);
      a.s[k][i] = sc;
      a.t[k][i] = a.b[k][i] - a.m[k][i] * sc;
    }
  }
  if (i < 1536) a.dotqkv[i] = 0.f;
  if (i < 2048) a.dot1[i] = 0.f;
  if (i < 512) {
    float w = a.wtq[i];
    float sp = (w > 20.f) ? w : log1pf(expf(w));
    float be = 1.f - 1.f / (sp + 1.f);
    a.betaq[i] = fminf(fmaxf(be, 0.f), 0.9999f);
    w = a.wtk[i];
    sp = (w > 20.f) ? w : log1pf(expf(w));
    be = 1.f - 1.f / (sp + 1.f);
    a.betak[i] = fminf(fmaxf(be, 0.f), 0.9999f);
  }
}

// -------- coalesced fold: 64x64 LDS-transpose tile; W[K][Nn] -> WT bf16 [Nn][K] --------
__global__ void fold_wT2(const float* __restrict__ W, int K, int Nn,
                         const float* scin, const float* scout,
                         const float* tin, float* dotacc,
                         unsigned short* __restrict__ WT) {
  __shared__ float tile[64][65];
  __shared__ float dsum[4][64];
  const int j0 = blockIdx.x * 64, d0 = blockIdx.y * 64;
  const int tid = threadIdx.x;
  const int j = tid & 63, r = tid >> 6;
  float dpart = 0.f;
  #pragma unroll
  for (int i = 0; i < 16; ++i) {
    int dd = i * 4 + r;
    float w = W[(size_t)(d0 + dd) * Nn + j0 + j];
    tile[dd][j] = w;
    if (tin) dpart += tin[d0 + dd] * w;
  }
  if (tin) dsum[r][j] = dpart;
  __syncthreads();
  if (tin && r == 0)
    atomicAdd(&dotacc[j0 + j], dsum[0][j] + dsum[1][j] + dsum[2][j] + dsum[3][j]);
  const int d = j;
  const float si = scin ? scin[d0 + d] : 1.f;
  #pragma unroll
  for (int i = 0; i < 16; ++i) {
    int jj = i * 4 + r;
    float so = scout ? scout[j0 + jj] : 1.f;
    WT[(size_t)(j0 + jj) * K + d0 + d] = f2bits(tile[d][jj] * si * so);
  }
}

// -------- legacy per-column fold (kept for tiny rffW: K=64, N=48) --------
__global__ void fold_wT(const float* __restrict__ W, int K, int Nn,
                        unsigned short* __restrict__ WT) {
  int j = blockIdx.x;
  int lane = threadIdx.x;   // 64
  for (int dd = lane; dd < K; dd += 64)
    WT[(size_t)j * K + dd] = f2bits(W[(size_t)dd * Nn + j]);
}

// -------- bias finalize --------
struct BiasArgs {
  const float *dotqkv, *dot1, *bv, *fc1b, *fc2b;
  const float *s1, *t1, *s2, *t2, *s3, *t3, *s5, *t5, *s6, *t6;
  float *c_qkv, *c1, *c2;
};
__global__ void bias_fin(BiasArgs a) {
  int i = blockIdx.x * 256 + threadIdx.x;   // 0..2047
  if (i < 512) {
    a.c_qkv[i]        = a.s1[i] * a.dotqkv[i]        + a.t1[i];
    a.c_qkv[512 + i]  = a.s2[i] * a.dotqkv[512 + i]  + a.t2[i];
    a.c_qkv[1024 + i] = a.s3[i] * (a.dotqkv[1024 + i] + a.bv[i]) + a.t3[i];
    a.c2[i]           = a.s6[i] * a.fc2b[i] + a.t6[i];
  }
  if (i < 2048) a.c1[i] = a.s5[i] * (a.dot1[i] + a.fc1b[i]) + a.t5[i];
}

// ---------------- cast x f32 -> bf16 ----------------
__global__ void cast_x(const float* __restrict__ x, unsigned short* __restrict__ xb, int n) {
  int i = (blockIdx.x * blockDim.x + threadIdx.x) * 4;
  if (i >= n) return;
  float4 v = *(const float4*)(x + i);
  u16x4 o = {f2bits(v.x), f2bits(v.y), f2bits(v.z), f2bits(v.w)};
  *(u16x4*)(xb + i) = o;
}

// ---------------- GEMM: C[M,N] = A[M,K](bf16) * BT[N,K](bf16)^T + bias, fused epilogues --------
// MODE 0: outb = bf16(acc+bias)
// MODE 1: outb = bf16(us2f(xresb) + acc + bias)
// MODE 2: outb = bf16(gelu(acc+bias))   (sigmoid-form tanh gelu)
// MODE 3: outf = us2f(xresb) + acc + bias
template <int MODE>
__global__ __launch_bounds__(256, 4) void gemm_bf16(
    const unsigned short* __restrict__ A, const unsigned short* __restrict__ BT,
    int K, int Nn, const float* __restrict__ bias,
    const unsigned short* __restrict__ xresb,
    float* __restrict__ outf, unsigned short* __restrict__ outb) {
  __shared__ __align__(16) unsigned short Ab[2][128 * 32];
  __shared__ __align__(16) unsigned short Bb[2][128 * 32];
  const int tid = threadIdx.x, w = tid >> 6, lane = tid & 63;
  const int l15 = lane & 15, lg = lane >> 4;
  const int row0 = blockIdx.x * 128, col0 = blockIdx.y * 128;
  const int wr = w >> 1, wc = w & 1;
  const unsigned short* Abase = A + (size_t)row0 * K;
  const unsigned short* Bbase = BT + (size_t)col0 * K;

  auto stage = [&](int buf, int kt) {
    #pragma unroll
    for (int s = 0; s < 2; ++s) {
      int c = s * 256 + w * 64 + lane;
      gload_lds16(Abase + (size_t)(c >> 2) * K + kt * 32 + (c & 3) * 8,
                  &Ab[buf][(s * 256 + w * 64) * 8]);
      gload_lds16(Bbase + (size_t)(c >> 2) * K + kt * 32 + (c & 3) * 8,
                  &Bb[buf][(s * 256 + w * 64) * 8]);
    }
  };

  const f32x4 fz = {0.f, 0.f, 0.f, 0.f};
  f32x4 acc[4][4];
  #pragma unroll
  for (int m = 0; m < 4; ++m)
    #pragma unroll
    for (int n = 0; n < 4; ++n) acc[m][n] = fz;

  stage(0, 0);
  __syncthreads();
  int cur = 0;
  const int nt = K >> 5;
  for (int kt = 0; kt < nt; ++kt) {
    if (kt + 1 < nt) stage(cur ^ 1, kt + 1);
    s16x8 af[4], bf[4];
    #pragma unroll
    for (int m = 0; m < 4; ++m)
      af[m] = *(const s16x8*)&Ab[cur][(wr * 64 + m * 16 + l15) * 32 + lg * 8];
    #pragma unroll
    for (int n = 0; n < 4; ++n)
      bf[n] = *(const s16x8*)&Bb[cur][(wc * 64 + n * 16 + l15) * 32 + lg * 8];
    #pragma unroll
    for (int m = 0; m < 4; ++m)
      #pragma unroll
      for (int n = 0; n < 4; ++n)
        acc[m][n] = __builtin_amdgcn_mfma_f32_16x16x32_bf16(af[m], bf[n], acc[m][n], 0, 0, 0);
    __syncthreads();
    cur ^= 1;
  }

  #pragma unroll
  for (int m = 0; m < 4; ++m) {
    #pragma unroll
    for (int q = 0; q < 4; ++q) {
      int row = row0 + wr * 64 + m * 16 + lg * 4 + q;
      #pragma unroll
      for (int n = 0; n < 4; ++n) {
        int col = col0 + wc * 64 + n * 16 + l15;
        float v = acc[m][n][q] + bias[col];
        size_t idx = (size_t)row * Nn + col;
        if constexpr (MODE == 0) {
          outb[idx] = f2bits(v);
        } else if constexpr (MODE == 1) {
          outb[idx] = f2bits(us2f(xresb[idx]) + v);
        } else if constexpr (MODE == 2) {
          float u2 = v * 1.5957691216f * (1.f + 0.044715f * v * v);
          float gl = v / (1.f + __expf(-u2));
          outb[idx] = f2bits(gl);
        } else {
          outf[idx] = us2f(xresb[idx]) + v;
        }
      }
    }
  }
}

// ---------------- membrane EMA scan over L, IN-PLACE, coalesced, 8-wide batched ----------------
__global__ __launch_bounds__(1024) void mem_scan2(unsigned short* __restrict__ qkv,
                         const float* __restrict__ betaq, const float* __restrict__ betak) {
  __shared__ float carry[16][64];
  __shared__ float pre[16][64];
  int cg = blockIdx.x & 15, b = blockIdx.x >> 4;
  int w = threadIdx.x >> 6, lane = threadIdx.x & 63;
  int ch = cg * 64 + lane;
  const float beta = (ch < 512) ? betaq[ch] : betak[ch - 512];
  const float om = 1.f - beta;
  unsigned short* base = qkv + (size_t)b * 1536 + ch;
  const size_t rs = 16 * 1536;     // shorts per L-step
  const int l0 = w * 128;

  float m = 0.f;
  for (int i = 0; i < 128; i += 8) {
    float v[8];
    #pragma unroll
    for (int j = 0; j < 8; ++j) v[j] = us2f(base[(size_t)(l0 + i + j) * rs]);
    #pragma unroll
    for (int j = 0; j < 8; ++j) m = beta * m + om * v[j];
  }
  carry[w][lane] = m;
  __syncthreads();
  if (w == 0) {
    float pw = beta;
    #pragma unroll
    for (int t = 0; t < 7; ++t) pw *= pw;   // beta^128
    float run = 0.f;
    for (int cc = 0; cc < 16; ++cc) {
      pre[cc][lane] = run;
      run = carry[cc][lane] + pw * run;
    }
  }
  __syncthreads();
  m = pre[w][lane];
  for (int i = 0; i < 128; i += 8) {
    float v[8];
    #pragma unroll
    for (int j = 0; j < 8; ++j) v[j] = us2f(base[(size_t)(l0 + i + j) * rs]);
    #pragma unroll
    for (int j = 0; j < 8; ++j) {
      m = beta * m + om * v[j];
      base[(size_t)(l0 + i + j) * rs] = f2bits(m);
    }
  }
}

// ---------------- transpose v: qkv v-cols -> vT[b,h,dh][L] ----------------
__global__ void transpose_v(const unsigned short* __restrict__ qkv, unsigned short* __restrict__ vT) {
  __shared__ __align__(16) unsigned short tile[64][72];
  int bid = blockIdx.x;
  int lt = bid & 31, h = (bid >> 5) & 7, b = bid >> 8;
  int l0 = lt * 64;
  int tid = threadIdx.x;
  int r = tid >> 2, cg = (tid & 3) * 16;
  const unsigned short* src = qkv + (size_t)((l0 + r) * 16 + b) * 1536 + 1024 + h * 64 + cg;
  *(s16x8*)&tile[r][cg] = *(const s16x8*)(src);
  *(s16x8*)&tile[r][cg + 8] = *(const s16x8*)(src + 8);
  __syncthreads();
  int dh = tid >> 2, lgp = (tid & 3) * 16;
  s16x8 o0, o1;
  #pragma unroll
  for (int j = 0; j < 8; ++j) {
    o0[j] = (short)tile[lgp + j][dh];
    o1[j] = (short)tile[lgp + 8 + j][dh];
  }
  unsigned short* dstp = vT + (size_t)((b * 8 + h) * 64 + dh) * 2048 + l0 + lgp;
  *(s16x8*)dstp = o0;
  *(s16x8*)(dstp + 8) = o1;
}

// ---------------- RFF linear attention phase A: KV + Ksum partials (no global atomics) ----------
__global__ __launch_bounds__(512, 1) void attn_A(
    const unsigned short* __restrict__ qkv, const unsigned short* __restrict__ vT,
    const unsigned short* __restrict__ WrT, const float* __restrict__ rffb,
    float* __restrict__ KVg, float* __restrict__ Ksumg) {
  __shared__ float KV[48][64];
  __shared__ float Ksum[48];
  __shared__ __align__(16) unsigned short phiT[8][48][72];

  const int tid = threadIdx.x;
  const int w = tid >> 6, lane = tid & 63, l15 = lane & 15, lg = lane >> 4;
  const int bh = blockIdx.x, b = bh >> 3, h = bh & 7;
  const int half = blockIdx.y;
  const f32x4 fz = {0.f, 0.f, 0.f, 0.f};
  constexpr float ISR = 0.14433756729740643f;   // 1/sqrt(48)

  for (int i = tid; i < 48 * 64; i += 512) (&KV[0][0])[i] = 0.f;
  if (tid < 48) Ksum[tid] = 0.f;
  __syncthreads();

  s16x8 wf[3][2];
  float bias_n[3];
  #pragma unroll
  for (int n = 0; n < 3; ++n) {
    int r = n * 16 + l15;
    bias_n[n] = rffb[h * 48 + r];
    #pragma unroll
    for (int ks = 0; ks < 2; ++ks)
      wf[n][ks] = *(const s16x8*)(WrT + (size_t)(h * 48 + r) * 64 + ks * 32 + lg * 8);
  }

  f32x4 kv[3][4];
  #pragma unroll
  for (int mm = 0; mm < 3; ++mm)
    #pragma unroll
    for (int nn = 0; nn < 4; ++nn) kv[mm][nn] = fz;
  float ks_acc[3] = {0.f, 0.f, 0.f};
  const size_t vbase = (size_t)(b * 8 + h) * 64 * 2048;

  for (int c = half * 16 + w; c < half * 16 + 16; c += 8) {
    const int l0 = c * 64;
    s16x8 kf[4][2];
    #pragma unroll
    for (int m = 0; m < 4; ++m) {
      size_t ro = (size_t)((l0 + m * 16 + l15) * 16 + b) * 1536 + 512 + h * 64;
      #pragma unroll
      for (int ks = 0; ks < 2; ++ks)
        kf[m][ks] = *(const s16x8*)(qkv + ro + ks * 32 + lg * 8);
    }
    f32x4 p[4][3];
    #pragma unroll
    for (int m = 0; m < 4; ++m)
      #pragma unroll
      for (int n = 0; n < 3; ++n) {
        p[m][n] = fz + bias_n[n];
        #pragma unroll
        for (int ks = 0; ks < 2; ++ks)
          p[m][n] = __builtin_amdgcn_mfma_f32_16x16x32_bf16(kf[m][ks], wf[n][ks], p[m][n], 0, 0, 0);
      }
    #pragma unroll
    for (int m = 0; m < 4; ++m)
      #pragma unroll
      for (int n = 0; n < 3; ++n) {
        u16x4 pk;
        #pragma unroll
        for (int q = 0; q < 4; ++q) {
          float pv = p[m][n][q];
          float ph = (pv > 0.f ? pv + 1.000001f : __expf(pv) + 1e-6f) * ISR;
          ks_acc[n] += ph;
          pk[q] = f2bits(ph);
        }
        *(u16x4*)&phiT[w][n * 16 + l15][m * 16 + lg * 4] = pk;
      }
    s16x8 pf[3][2], vf[4][2];
    #pragma unroll
    for (int mm = 0; mm < 3; ++mm)
      #pragma unroll
      for (int ks = 0; ks < 2; ++ks)
        pf[mm][ks] = *(const s16x8*)&phiT[w][mm * 16 + l15][ks * 32 + lg * 8];
    #pragma unroll
    for (int nn = 0; nn < 4; ++nn)
      #pragma unroll
      for (int ks = 0; ks < 2; ++ks)
        vf[nn][ks] = *(const s16x8*)(vT + vbase + (size_t)(nn * 16 + l15) * 2048 + l0 + ks * 32 + lg * 8);
    #pragma unroll
    for (int mm = 0; mm < 3; ++mm)
      #pragma unroll
      for (int nn = 0; nn < 4; ++nn)
        #pragma unroll
        for (int ks = 0; ks < 2; ++ks)
          kv[mm][nn] = __builtin_amdgcn_mfma_f32_16x16x32_bf16(pf[mm][ks], vf[nn][ks], kv[mm][nn], 0, 0, 0);
  }
  #pragma unroll
  for (int n = 0; n < 3; ++n) {
    float t = ks_acc[n];
    t += __shfl_xor(t, 16);
    t += __shfl_xor(t, 32);
    if (lane < 16) atomicAdd(&Ksum[n * 16 + lane], t);
  }
  #pragma unroll
  for (int mm = 0; mm < 3; ++mm)
    #pragma unroll
    for (int nn = 0; nn < 4; ++nn)
      #pragma unroll
      for (int q = 0; q < 4; ++q)
        atomicAdd(&KV[mm * 16 + lg * 4 + q][nn * 16 + l15], kv[mm][nn][q]);
  __syncthreads();

  float* dst = KVg + (size_t)(half * 128 + bh) * 3072;
  for (int i = tid; i < 48 * 64; i += 512) dst[i] = (&KV[0][0])[i];
  if (tid < 48) Ksumg[(half * 128 + bh) * 48 + tid] = Ksum[tid];
}

// ---------------- RFF linear attention phase B: phi_q, num/den, output ----------------
__global__ __launch_bounds__(512, 1) void attn_B(
    const unsigned short* __restrict__ qkv, const unsigned short* __restrict__ WrT,
    const float* __restrict__ rffb, const float* __restrict__ KVg,
    const float* __restrict__ Ksumg, unsigned short* __restrict__ attn) {
  __shared__ __align__(16) unsigned short KVT[80][72];
  __shared__ __align__(16) unsigned short phiQ[8][64][72];

  const int tid = threadIdx.x;
  const int w = tid >> 6, lane = tid & 63, l15 = lane & 15, lg = lane >> 4;
  const int bh = blockIdx.x, b = bh >> 3, h = bh & 7;
  const int half = blockIdx.y;
  const f32x4 fz = {0.f, 0.f, 0.f, 0.f};
  constexpr float ISR = 0.14433756729740643f;   // 1/sqrt(48)

  for (int i = tid; i < 8 * 64 * 72; i += 512) (&phiQ[0][0][0])[i] = 0;
  for (int i = tid; i < 80 * 72; i += 512) {
    int dhe = i / 72, rr = i - dhe * 72;
    float val = 0.f;
    if (rr < 48) {
      if (dhe < 64)
        val = KVg[(size_t)bh * 3072 + rr * 64 + dhe] + KVg[(size_t)(128 + bh) * 3072 + rr * 64 + dhe];
      else if (dhe == 64)
        val = fmaxf(Ksumg[bh * 48 + rr] + Ksumg[(128 + bh) * 48 + rr], 1e-6f);
    }
    (&KVT[0][0])[i] = f2bits(val);
  }
  __syncthreads();

  s16x8 wf[3][2];
  float bias_n[3];
  #pragma unroll
  for (int n = 0; n < 3; ++n) {
    int r = n * 16 + l15;
    bias_n[n] = rffb[h * 48 + r];
    #pragma unroll
    for (int ks = 0; ks < 2; ++ks)
      wf[n][ks] = *(const s16x8*)(WrT + (size_t)(h * 48 + r) * 64 + ks * 32 + lg * 8);
  }

  for (int c = half * 16 + w; c < half * 16 + 16; c += 8) {
    const int l0 = c * 64;
    s16x8 qf[4][2];
    #pragma unroll
    for (int m = 0; m < 4; ++m) {
      size_t ro = (size_t)((l0 + m * 16 + l15) * 16 + b) * 1536 + h * 64;
      #pragma unroll
      for (int ks = 0; ks < 2; ++ks)
        qf[m][ks] = *(const s16x8*)(qkv + ro + ks * 32 + lg * 8);
    }
    f32x4 p[4][3];
    #pragma unroll
    for (int m = 0; m < 4; ++m)
      #pragma unroll
      for (int n = 0; n < 3; ++n) {
        p[m][n] = fz + bias_n[n];
        #pragma unroll
        for (int ks = 0; ks < 2; ++ks)
          p[m][n] = __builtin_amdgcn_mfma_f32_16x16x32_bf16(qf[m][ks], wf[n][ks], p[m][n], 0, 0, 0);
      }
    #pragma unroll
    for (int m = 0; m < 4; ++m)
      #pragma unroll
      for (int n = 0; n < 3; ++n)
        #pragma unroll
        for (int q = 0; q < 4; ++q) {
          float pv = p[m][n][q];
          float ph = (pv > 0.f ? pv + 1.000001f : __expf(pv) + 1e-6f) * ISR;
          phiQ[w][m * 16 + lg * 4 + q][n * 16 + l15] = f2bits(ph);
        }
    s16x8 af[4][2], bv8[5][2];
    #pragma unroll
    for (int m = 0; m < 4; ++m)
      #pragma unroll
      for (int ks = 0; ks < 2; ++ks)
        af[m][ks] = *(const s16x8*)&phiQ[w][m * 16 + l15][ks * 32 + lg * 8];
    #pragma unroll
    for (int n5 = 0; n5 < 5; ++n5)
      #pragma unroll
      for (int ks = 0; ks < 2; ++ks)
        bv8[n5][ks] = *(const s16x8*)&KVT[n5 * 16 + l15][ks * 32 + lg * 8];
    f32x4 o[4][5];
    #pragma unroll
    for (int m = 0; m < 4; ++m)
      #pragma unroll
      for (int n5 = 0; n5 < 5; ++n5) {
        o[m][n5] = fz;
        #pragma unroll
        for (int ks = 0; ks < 2; ++ks)
          o[m][n5] = __builtin_amdgcn_mfma_f32_16x16x32_bf16(af[m][ks], bv8[n5][ks], o[m][n5], 0, 0, 0);
      }
    #pragma unroll
    for (int m = 0; m < 4; ++m)
      #pragma unroll
      for (int q = 0; q < 4; ++q) {
        float den = __shfl(o[m][4][q], lane & 48);
        float inv = 1.f / (den + 1e-6f);
        int gl = l0 + m * 16 + lg * 4 + q;
        size_t ob = (size_t)(gl * 16 + b) * 512 + h * 64;
        #pragma unroll
        for (int n = 0; n < 4; ++n)
          attn[ob + n * 16 + l15] = f2bits(o[m][n][q] * inv);
      }
  }
}

// ---------------- host ----------------
extern "C" void kernel_launch(void* const* d_in, const int* in_sizes, int n_in,
                              void* d_out, int out_size, void* d_ws, size_t ws_size,
                              hipStream_t stream) {
  (void)in_sizes; (void)n_in; (void)out_size; (void)ws_size;
  const float* x = (const float*)d_in[0];
  const float* Wq = (const float*)d_in[29];
  const float* Wk = (const float*)d_in[30];
  const float* Wv = (const float*)d_in[31];
  const float* bv = (const float*)d_in[32];
  const float* Wo = (const float*)d_in[33];
  const float* bo = (const float*)d_in[34];
  const float* wtq = (const float*)d_in[35];
  const float* wtk = (const float*)d_in[36];
  const float* rffW = (const float*)d_in[37];
  const float* rffb = (const float*)d_in[38];
  const float* fc1W = (const float*)d_in[39];
  const float* fc1b = (const float*)d_in[40];
  const float* fc2W = (const float*)d_in[41];
  const float* fc2b = (const float*)d_in[42];

  char* cur = (char*)d_ws;
  auto alloc = [&](size_t bytes) -> char* {
    char* r = cur;
    cur += (bytes + 255) & ~(size_t)255;
    return r;
  };
  float* sv_[7];
  float* tv_[7];
  const int dims[7] = {512, 512, 512, 512, 512, 2048, 512};
  for (int k = 0; k < 7; ++k) {
    sv_[k] = (float*)alloc(dims[k] * 4);
    tv_[k] = (float*)alloc(dims[k] * 4);
  }
  float* betaq = (float*)alloc(512 * 4);
  float* betak = (float*)alloc(512 * 4);
  float* c_qkv = (float*)alloc(1536 * 4);
  float* c1 = (float*)alloc(2048 * 4);
  float* c2 = (float*)alloc(512 * 4);
  float* dotqkv = (float*)alloc(1536 * 4);
  float* dot1   = (float*)alloc(2048 * 4);
  float* KVg   = (float*)alloc((size_t)256 * 3072 * 4);   // [half*128+bh][3072]
  float* Ksumg = (float*)alloc((size_t)256 * 48 * 4);
  unsigned short* AqkvT = (unsigned short*)alloc((size_t)1536 * 512 * 2);
  unsigned short* WoT   = (unsigned short*)alloc((size_t)512 * 512 * 2);
  unsigned short* A1T   = (unsigned short*)alloc((size_t)2048 * 512 * 2);
  unsigned short* A2T   = (unsigned short*)alloc((size_t)512 * 2048 * 2);
  unsigned short* WrT   = (unsigned short*)alloc((size_t)8 * 48 * 64 * 2);
  // big buffers (qkv and vT MUST be adjacent: g overlays both exactly)
  unsigned short* qkv   = (unsigned short*)alloc((size_t)NR * 1536 * 2);  // 96 MiB
  unsigned short* vT    = (unsigned short*)alloc((size_t)NR * 512 * 2);   // 32 MiB: vT then attn-out
  unsigned short* xb    = (unsigned short*)alloc((size_t)NR * 512 * 2);   // 32 MiB: bf16(x), lives to wo
  unsigned short* xrb   = (unsigned short*)alloc((size_t)NR * 512 * 2);   // 32 MiB
  unsigned short* attnO = vT;          // attn output reuses vT (dead after attn_A)
  unsigned short* g = qkv;             // fc1-out [NR][2048] bf16 = 128 MiB over qkv+vT (both dead)

  PrepArgs pa;
  for (int k = 0; k < 7; ++k) {
    pa.g[k] = (const float*)d_in[1 + k * 4 + 0];
    pa.b[k] = (const float*)d_in[1 + k * 4 + 1];
    pa.m[k] = (const float*)d_in[1 + k * 4 + 2];
    pa.v[k] = (const float*)d_in[1 + k * 4 + 3];
    pa.s[k] = sv_[k];
    pa.t[k] = tv_[k];
  }
  pa.wtq = wtq; pa.wtk = wtk; pa.betaq = betaq; pa.betak = betak;
  pa.dotqkv = dotqkv; pa.dot1 = dot1;

  prep_vectors<<<8, 256, 0, stream>>>(pa);
  // coalesced folds (64x64 tiles): grid (Nn/64, K/64)
  fold_wT2<<<dim3(8, 8), 256, 0, stream>>>(Wq, 512, 512, sv_[0], sv_[1], tv_[0], dotqkv, AqkvT);
  fold_wT2<<<dim3(8, 8), 256, 0, stream>>>(Wk, 512, 512, sv_[0], sv_[2], tv_[0], dotqkv + 512, AqkvT + 512 * 512);
  fold_wT2<<<dim3(8, 8), 256, 0, stream>>>(Wv, 512, 512, sv_[0], sv_[3], tv_[0], dotqkv + 1024, AqkvT + 1024 * 512);
  fold_wT2<<<dim3(8, 8), 256, 0, stream>>>(Wo, 512, 512, nullptr, nullptr, nullptr, nullptr, WoT);
  fold_wT2<<<dim3(32, 8), 256, 0, stream>>>(fc1W, 512, 2048, sv_[4], sv_[5], tv_[4], dot1, A1T);
  fold_wT2<<<dim3(8, 32), 256, 0, stream>>>(fc2W, 2048, 512, nullptr, sv_[6], nullptr, nullptr, A2T);
  for (int h = 0; h < 8; ++h)
    fold_wT<<<48, 64, 0, stream>>>(rffW + h * 64 * 48, 64, 48, WrT + h * 48 * 64);

  BiasArgs ba;
  ba.dotqkv = dotqkv; ba.dot1 = dot1; ba.bv = bv; ba.fc1b = fc1b; ba.fc2b = fc2b;
  ba.s1 = sv_[1]; ba.t1 = tv_[1]; ba.s2 = sv_[2]; ba.t2 = tv_[2]; ba.s3 = sv_[3]; ba.t3 = tv_[3];
  ba.s5 = sv_[5]; ba.t5 = tv_[5]; ba.s6 = sv_[6]; ba.t6 = tv_[6];
  ba.c_qkv = c_qkv; ba.c1 = c1; ba.c2 = c2;
  bias_fin<<<8, 256, 0, stream>>>(ba);

  cast_x<<<16384, 256, 0, stream>>>(x, xb, NR * 512);
  gemm_bf16<0><<<dim3(256, 12), 256, 0, stream>>>(xb, AqkvT, 512, 1536, c_qkv, nullptr, nullptr, qkv);
  mem_scan2<<<256, 1024, 0, stream>>>(qkv, betaq, betak);
  transpose_v<<<4096, 256, 0, stream>>>(qkv, vT);
  attn_A<<<dim3(128, 2), 512, 0, stream>>>(qkv, vT, WrT, rffb, KVg, Ksumg);
  attn_B<<<dim3(128, 2), 512, 0, stream>>>(qkv, WrT, rffb, KVg, Ksumg, attnO);
  gemm_bf16<1><<<dim3(256, 4), 256, 0, stream>>>(attnO, WoT, 512, 512, bo, xb, nullptr, xrb);
  gemm_bf16<2><<<dim3(256, 16), 256, 0, stream>>>(xrb, A1T, 512, 2048, c1, nullptr, nullptr, g);
  gemm_bf16<3><<<dim3(256, 4), 256, 0, stream>>>(g, A2T, 2048, 512, c2, xrb, (float*)d_out, nullptr);
}